// Round 3
// baseline (221.934 us; speedup 1.0000x reference)
//
#include <hip/hip_runtime.h>
#include <math.h>

// One thread per juv position (j*49+u*7+v, 392 total) per group element gi.
// Taps computed ONCE per thread in registers (math byte-identical to the
// verified round-2 literal kernel), then a 64-channel loop of
// 8 gathers + 8 FMA + 1 coalesced store per iteration.
//
// out flat: ((((o*8 + gi)*128 + ic)*8 + j)*7 + u)*7 + v
// sig flat: ((o*128 + ic)*8 + d)*49 + h*7 + w

constexpr int BLOCK = 448;          // 7 waves; lanes 392..447 idle (12.5%)
constexpr int JUV = 392;
constexpr int CH_PER_BLOCK = 64;    // stays within one 'o' (64 | 128)

__global__ __launch_bounds__(BLOCK)
void lift_reg(const float* __restrict__ sig, float* __restrict__ out) {
  const int juv = threadIdx.x;
  if (juv >= JUV) return;

  const int bid   = blockIdx.x;
  const int gi    = bid & 7;
  const int chunk = bid >> 3;            // 0..255
  const int c0    = chunk * CH_PER_BLOCK;

  // decode juv -> (j,u,v)
  int j  = juv / 49;
  int uv = juv - j * 49;
  int uu = uv / 7;
  int vv = uv - uu * 7;

  // ================= tap computation (verified math from round 2) ===========
  const float TWO_PI_F = 6.28318530717958647692f;
  const float STEP = TWO_PI_F / 8.0f;

  float ti = (float)gi * STEP;
  float tj = (float)j  * STEP;

  // ---- D (group) axis ----
  float tH = fmodf(tj - ti, TWO_PI_F);
  if (tH < 0.0f) tH += TWO_PI_F;
  const float largest = TWO_PI_F * 7.0f / 8.0f;
  float cD = 2.0f * tH / largest - 1.0f;
  float posD = (cD + 1.0f) * 0.5f * 7.0f;
  float flD = floorf(posD);
  float fd  = posD - flD;
  int dlo = (int)flD, dhi = dlo + 1;
  float wd0 = (dlo >= 0 && dlo <= 7) ? (1.0f - fd) : 0.0f;
  float wd1 = (dhi >= 0 && dhi <= 7) ? fd : 0.0f;
  int d0 = min(max(dlo, 0), 7) * 49;
  int d1 = min(max(dhi, 0), 7) * 49;

  // ---- rotation by inverse(e_i) ----
  float inv = fmodf(-ti, TWO_PI_F);
  if (inv < 0.0f) inv += TWO_PI_F;
  float cs = cosf(inv), sn = sinf(inv);
  float gx = (float)(uu - 3) * (1.0f / 3.0f);
  float gy = (float)(vv - 3) * (1.0f / 3.0f);
  float rx = cs * gx - sn * gy;
  float ry = sn * gx + cs * gy;

  // ---- H axis (rx) ----
  float posH = (rx + 1.0f) * 0.5f * 6.0f;
  float flH = floorf(posH);
  float fh  = posH - flH;
  int hlo = (int)flH, hhi = hlo + 1;
  float wh0 = (hlo >= 0 && hlo <= 6) ? (1.0f - fh) : 0.0f;
  float wh1 = (hhi >= 0 && hhi <= 6) ? fh : 0.0f;
  int h0 = min(max(hlo, 0), 6) * 7;
  int h1 = min(max(hhi, 0), 6) * 7;

  // ---- W axis (ry) ----
  float posW = (ry + 1.0f) * 0.5f * 6.0f;
  float flW = floorf(posW);
  float fw  = posW - flW;
  int wlo = (int)flW, whi = wlo + 1;
  float wq0 = (wlo >= 0 && wlo <= 6) ? (1.0f - fw) : 0.0f;
  float wq1 = (whi >= 0 && whi <= 6) ? fw : 0.0f;
  int q0 = min(max(wlo, 0), 6);
  int q1 = min(max(whi, 0), 6);

  // ---- fold into 8 offsets + 8 weights (loop-invariant registers) ----
  float a00 = wd0 * wh0, a01 = wd0 * wh1;
  float a10 = wd1 * wh0, a11 = wd1 * wh1;
  float w000 = a00 * wq0, w001 = a00 * wq1;
  float w010 = a01 * wq0, w011 = a01 * wq1;
  float w100 = a10 * wq0, w101 = a10 * wq1;
  float w110 = a11 * wq0, w111 = a11 * wq1;
  int o000 = d0 + h0 + q0, o001 = d0 + h0 + q1;
  int o010 = d0 + h1 + q0, o011 = d0 + h1 + q1;
  int o100 = d1 + h0 + q0, o101 = d1 + h0 + q1;
  int o110 = d1 + h1 + q0, o111 = d1 + h1 + q1;
  // ==========================================================================

  const int o   = c0 >> 7;
  const int ic0 = c0 & 127;
  const float* __restrict__ sp = sig + (size_t)c0 * JUV;
  float* __restrict__ op = out + (size_t)((o * 8 + gi) * 128 + ic0) * JUV + juv;

  #pragma unroll 4
  for (int c = 0; c < CH_PER_BLOCK; ++c) {
    float acc = sp[o000] * w000 + sp[o001] * w001
              + sp[o010] * w010 + sp[o011] * w011
              + sp[o100] * w100 + sp[o101] * w101
              + sp[o110] * w110 + sp[o111] * w111;
    *op = acc;
    sp += JUV;
    op += JUV;
  }
}

extern "C" void kernel_launch(void* const* d_in, const int* in_sizes, int n_in,
                              void* d_out, int out_size, void* d_ws, size_t ws_size,
                              hipStream_t stream) {
  const float* w = (const float*)d_in[0];
  float* out = (float*)d_out;
  // 8 group elems x (16384 channels / 64 per block) = 2048 blocks
  const int blocks = 8 * (128 * 128 / CH_PER_BLOCK);
  hipLaunchKernelGGL(lift_reg, dim3(blocks), dim3(BLOCK), 0, stream, w, out);
}

// Round 4
// 128.010 us; speedup vs baseline: 1.7337x; 1.7337x over previous
//
#include <hip/hip_runtime.h>
#include <math.h>

// One thread per juv position (392/block-page) per gi; taps in registers;
// d-axis is mathematically integer => keep only the dominant d slice (other
// slice's weight is fp-epsilon <= ~8e-7). Even gi => rotation is an exact
// grid symmetry => single dominant tap (scaled permutation copy). Odd gi =>
// 2x2 spatial bilinear (4 taps). Tap math identical to the verified literal
// kernel; dominance selection only picks among the already-computed masked
// weights.
//
// out flat: ((((o*8 + gi)*128 + ic)*8 + j)*7 + u)*7 + v
// sig flat: ((o*128 + ic)*8 + d)*49 + h*7 + w

constexpr int BLOCK = 448;          // 7 waves; lanes 392..447 idle
constexpr int JUV = 392;
constexpr int CH_PER_BLOCK = 64;

__global__ __launch_bounds__(BLOCK)
void lift4(const float* __restrict__ sig, float* __restrict__ out) {
  const int juv = threadIdx.x;
  if (juv >= JUV) return;

  const int bid   = blockIdx.x;
  const int gi    = bid & 7;
  const int chunk = bid >> 3;            // 0..255
  const int c0    = chunk * CH_PER_BLOCK;

  int j  = juv / 49;
  int uv = juv - j * 49;
  int uu = uv / 7;
  int vv = uv - uu * 7;

  // ================= tap computation (verified math, round 2) ===============
  const float TWO_PI_F = 6.28318530717958647692f;
  const float STEP = TWO_PI_F / 8.0f;

  float ti = (float)gi * STEP;
  float tj = (float)j  * STEP;

  // ---- D (group) axis ----
  float tH = fmodf(tj - ti, TWO_PI_F);
  if (tH < 0.0f) tH += TWO_PI_F;
  const float largest = TWO_PI_F * 7.0f / 8.0f;
  float cD = 2.0f * tH / largest - 1.0f;
  float posD = (cD + 1.0f) * 0.5f * 7.0f;
  float flD = floorf(posD);
  float fd  = posD - flD;
  int dlo = (int)flD, dhi = dlo + 1;
  float wd0 = (dlo >= 0 && dlo <= 7) ? (1.0f - fd) : 0.0f;
  float wd1 = (dhi >= 0 && dhi <= 7) ? fd : 0.0f;
  int d0 = min(max(dlo, 0), 7) * 49;
  int d1 = min(max(dhi, 0), 7) * 49;

  // ---- rotation by inverse(e_i) ----
  float inv = fmodf(-ti, TWO_PI_F);
  if (inv < 0.0f) inv += TWO_PI_F;
  float cs = cosf(inv), sn = sinf(inv);
  float gx = (float)(uu - 3) * (1.0f / 3.0f);
  float gy = (float)(vv - 3) * (1.0f / 3.0f);
  float rx = cs * gx - sn * gy;
  float ry = sn * gx + cs * gy;

  // ---- H axis (rx) ----
  float posH = (rx + 1.0f) * 0.5f * 6.0f;
  float flH = floorf(posH);
  float fh  = posH - flH;
  int hlo = (int)flH, hhi = hlo + 1;
  float wh0 = (hlo >= 0 && hlo <= 6) ? (1.0f - fh) : 0.0f;
  float wh1 = (hhi >= 0 && hhi <= 6) ? fh : 0.0f;
  int h0 = min(max(hlo, 0), 6) * 7;
  int h1 = min(max(hhi, 0), 6) * 7;

  // ---- W axis (ry) ----
  float posW = (ry + 1.0f) * 0.5f * 6.0f;
  float flW = floorf(posW);
  float fw  = posW - flW;
  int wlo = (int)flW, whi = wlo + 1;
  float wq0 = (wlo >= 0 && wlo <= 6) ? (1.0f - fw) : 0.0f;
  float wq1 = (whi >= 0 && whi <= 6) ? fw : 0.0f;
  int q0 = min(max(wlo, 0), 6);
  int q1 = min(max(whi, 0), 6);
  // ==========================================================================

  // d-axis: dominant slice only (other slice weight is fp-epsilon)
  float Wd; int db;
  if (wd1 > wd0) { Wd = wd1; db = d1; } else { Wd = wd0; db = d0; }

  const int o   = c0 >> 7;
  const int ic0 = c0 & 127;
  const float* __restrict__ sp = sig + (size_t)c0 * JUV;
  float* __restrict__ op = out + (size_t)((o * 8 + gi) * 128 + ic0) * JUV + juv;

  if ((gi & 1) == 0) {
    // exact grid symmetry: single dominant tap per spatial axis
    float Wh; int hb;
    if (wh1 > wh0) { Wh = wh1; hb = h1; } else { Wh = wh0; hb = h0; }
    float Ww; int qb;
    if (wq1 > wq0) { Ww = wq1; qb = q1; } else { Ww = wq0; qb = q0; }
    const float W = Wd * Wh * Ww;
    const int off = db + hb + qb;
    #pragma unroll 8
    for (int c = 0; c < CH_PER_BLOCK; ++c) {
      __builtin_nontemporal_store(sp[off] * W, op);
      sp += JUV; op += JUV;
    }
  } else {
    // 2x2 spatial bilinear in the dominant d slice
    const float w00 = Wd * wh0 * wq0, w01 = Wd * wh0 * wq1;
    const float w10 = Wd * wh1 * wq0, w11 = Wd * wh1 * wq1;
    const int o00 = db + h0 + q0, o01 = db + h0 + q1;
    const int o10 = db + h1 + q0, o11 = db + h1 + q1;
    #pragma unroll 4
    for (int c = 0; c < CH_PER_BLOCK; ++c) {
      float acc = sp[o00] * w00 + sp[o01] * w01
                + sp[o10] * w10 + sp[o11] * w11;
      __builtin_nontemporal_store(acc, op);
      sp += JUV; op += JUV;
    }
  }
}

extern "C" void kernel_launch(void* const* d_in, const int* in_sizes, int n_in,
                              void* d_out, int out_size, void* d_ws, size_t ws_size,
                              hipStream_t stream) {
  const float* w = (const float*)d_in[0];
  float* out = (float*)d_out;
  const int blocks = 8 * (128 * 128 / CH_PER_BLOCK);  // 2048
  hipLaunchKernelGGL(lift4, dim3(blocks), dim3(BLOCK), 0, stream, w, out);
}

// Round 8
// 106.966 us; speedup vs baseline: 2.0748x; 1.1967x over previous
//
#include <hip/hip_runtime.h>
#include <math.h>

// EXACT copy of the verified round-4 kernel (lift4, passed @128us) with ONE
// change: the (gi, chunk) <- blockIdx decode is transposed so that the 8
// blocks sharing a channel chunk land on the SAME XCD (default dispatch
// round-robins blockIdx across the 8 XCDs; bids that are equal mod 8 share
// an XCD). gi = bid>>8, chunk = bid&255  =>  all 8 gi-readers of chunk X
// have bid % 8 == X % 8 -> one L2 fetch per chunk instead of 8 cross-XCD
// copies (r4 measured FETCH_SIZE = 107 MB vs 25.7 MB input).
// Pure bijection on (gi, chunk): zero semantic change vs the passing kernel.
//
// out flat: ((((o*8 + gi)*128 + ic)*8 + j)*7 + u)*7 + v
// sig flat: ((o*128 + ic)*8 + d)*49 + h*7 + w

constexpr int BLOCK = 448;          // 7 waves; lanes 392..447 idle
constexpr int JUV = 392;
constexpr int CH_PER_BLOCK = 64;

__global__ __launch_bounds__(BLOCK)
void lift8(const float* __restrict__ sig, float* __restrict__ out) {
  const int juv = threadIdx.x;
  if (juv >= JUV) return;

  const int bid   = blockIdx.x;
  const int gi    = bid >> 8;            // 0..7   (was: bid & 7)
  const int chunk = bid & 255;           // 0..255 (was: bid >> 3)
  const int c0    = chunk * CH_PER_BLOCK;

  int j  = juv / 49;
  int uv = juv - j * 49;
  int uu = uv / 7;
  int vv = uv - uu * 7;

  // ================= tap computation (verified math, round 2) ===============
  const float TWO_PI_F = 6.28318530717958647692f;
  const float STEP = TWO_PI_F / 8.0f;

  float ti = (float)gi * STEP;
  float tj = (float)j  * STEP;

  // ---- D (group) axis ----
  float tH = fmodf(tj - ti, TWO_PI_F);
  if (tH < 0.0f) tH += TWO_PI_F;
  const float largest = TWO_PI_F * 7.0f / 8.0f;
  float cD = 2.0f * tH / largest - 1.0f;
  float posD = (cD + 1.0f) * 0.5f * 7.0f;
  float flD = floorf(posD);
  float fd  = posD - flD;
  int dlo = (int)flD, dhi = dlo + 1;
  float wd0 = (dlo >= 0 && dlo <= 7) ? (1.0f - fd) : 0.0f;
  float wd1 = (dhi >= 0 && dhi <= 7) ? fd : 0.0f;
  int d0 = min(max(dlo, 0), 7) * 49;
  int d1 = min(max(dhi, 0), 7) * 49;

  // ---- rotation by inverse(e_i) ----
  float inv = fmodf(-ti, TWO_PI_F);
  if (inv < 0.0f) inv += TWO_PI_F;
  float cs = cosf(inv), sn = sinf(inv);
  float gx = (float)(uu - 3) * (1.0f / 3.0f);
  float gy = (float)(vv - 3) * (1.0f / 3.0f);
  float rx = cs * gx - sn * gy;
  float ry = sn * gx + cs * gy;

  // ---- H axis (rx) ----
  float posH = (rx + 1.0f) * 0.5f * 6.0f;
  float flH = floorf(posH);
  float fh  = posH - flH;
  int hlo = (int)flH, hhi = hlo + 1;
  float wh0 = (hlo >= 0 && hlo <= 6) ? (1.0f - fh) : 0.0f;
  float wh1 = (hhi >= 0 && hhi <= 6) ? fh : 0.0f;
  int h0 = min(max(hlo, 0), 6) * 7;
  int h1 = min(max(hhi, 0), 6) * 7;

  // ---- W axis (ry) ----
  float posW = (ry + 1.0f) * 0.5f * 6.0f;
  float flW = floorf(posW);
  float fw  = posW - flW;
  int wlo = (int)flW, whi = wlo + 1;
  float wq0 = (wlo >= 0 && wlo <= 6) ? (1.0f - fw) : 0.0f;
  float wq1 = (whi >= 0 && whi <= 6) ? fw : 0.0f;
  int q0 = min(max(wlo, 0), 6);
  int q1 = min(max(whi, 0), 6);
  // ==========================================================================

  // d-axis: dominant slice only (other slice weight is fp-epsilon)
  float Wd; int db;
  if (wd1 > wd0) { Wd = wd1; db = d1; } else { Wd = wd0; db = d0; }

  const int o   = c0 >> 7;
  const int ic0 = c0 & 127;
  const float* __restrict__ sp = sig + (size_t)c0 * JUV;
  float* __restrict__ op = out + (size_t)((o * 8 + gi) * 128 + ic0) * JUV + juv;

  if ((gi & 1) == 0) {
    // exact grid symmetry: single dominant tap per spatial axis
    float Wh; int hb;
    if (wh1 > wh0) { Wh = wh1; hb = h1; } else { Wh = wh0; hb = h0; }
    float Ww; int qb;
    if (wq1 > wq0) { Ww = wq1; qb = q1; } else { Ww = wq0; qb = q0; }
    const float W = Wd * Wh * Ww;
    const int off = db + hb + qb;
    #pragma unroll 8
    for (int c = 0; c < CH_PER_BLOCK; ++c) {
      __builtin_nontemporal_store(sp[off] * W, op);
      sp += JUV; op += JUV;
    }
  } else {
    // 2x2 spatial bilinear in the dominant d slice
    const float w00 = Wd * wh0 * wq0, w01 = Wd * wh0 * wq1;
    const float w10 = Wd * wh1 * wq0, w11 = Wd * wh1 * wq1;
    const int o00 = db + h0 + q0, o01 = db + h0 + q1;
    const int o10 = db + h1 + q0, o11 = db + h1 + q1;
    #pragma unroll 4
    for (int c = 0; c < CH_PER_BLOCK; ++c) {
      float acc = sp[o00] * w00 + sp[o01] * w01
                + sp[o10] * w10 + sp[o11] * w11;
      __builtin_nontemporal_store(acc, op);
      sp += JUV; op += JUV;
    }
  }
}

extern "C" void kernel_launch(void* const* d_in, const int* in_sizes, int n_in,
                              void* d_out, int out_size, void* d_ws, size_t ws_size,
                              hipStream_t stream) {
  const float* w = (const float*)d_in[0];
  float* out = (float*)d_out;
  const int blocks = 8 * (128 * 128 / CH_PER_BLOCK);  // 2048
  hipLaunchKernelGGL(lift8, dim3(blocks), dim3(BLOCK), 0, stream, w, out);
}

// Round 9
// 71.179 us; speedup vs baseline: 3.1180x; 1.5028x over previous
//
#include <hip/hip_runtime.h>
#include <math.h>

// Round-8 structure (PASSING, 107us) + LDS-staged gathers. ONE delta vs r8:
// the 16-channel chunk is staged to LDS with coalesced float4 loads (this
// exact staging pattern is exonerated by r5/r7 bit-identity), and the
// per-channel gathers read LDS instead of scattered L1/L2. gi comes from
// blockIdx (the fused-gi loop structure is abandoned — it carries an
// unlocated bug, r5/6/7 bit-identical failures).
//
// Block decode keeps the XCD property: blocks sharing a chunk have
// bid % 8 == chunk % 8 -> same XCD -> one L2 copy per chunk.
//
// out flat: ((((o*8 + gi)*128 + ic)*8 + j)*7 + u)*7 + v
// sig flat: ((o*128 + ic)*8 + d)*49 + h*7 + w

constexpr int BLOCK = 448;          // 7 waves; lanes 392..447 idle in compute
constexpr int JUV = 392;
constexpr int C = 16;               // channels per block (16 | 128 -> one 'o')

__global__ __launch_bounds__(BLOCK)
void lift9(const float* __restrict__ sig, float* __restrict__ out) {
  __shared__ __align__(16) float lds[C * JUV];   // 25,088 B -> 4 blocks/CU

  const int bid   = blockIdx.x;
  const int gi    = bid >> 10;           // 0..7
  const int chunk = bid & 1023;          // 0..1023
  const int c0    = chunk * C;

  // ---- stage chunk: coalesced float4 (pattern exonerated by r5/r7) ----
  {
    const float4* src4 = (const float4*)(sig + (size_t)c0 * JUV);
    float4* dst4 = (float4*)lds;
    for (int idx = threadIdx.x; idx < C * JUV / 4; idx += BLOCK)
      dst4[idx] = src4[idx];
  }
  __syncthreads();

  const int juv = threadIdx.x;
  if (juv >= JUV) return;

  int j  = juv / 49;
  int uv = juv - j * 49;
  int uu = uv / 7;
  int vv = uv - uu * 7;

  // ================= tap computation (verified math, rounds 2-8) ===========
  const float TWO_PI_F = 6.28318530717958647692f;
  const float STEP = TWO_PI_F / 8.0f;

  float ti = (float)gi * STEP;
  float tj = (float)j  * STEP;

  // ---- D (group) axis ----
  float tH = fmodf(tj - ti, TWO_PI_F);
  if (tH < 0.0f) tH += TWO_PI_F;
  const float largest = TWO_PI_F * 7.0f / 8.0f;
  float cD = 2.0f * tH / largest - 1.0f;
  float posD = (cD + 1.0f) * 0.5f * 7.0f;
  float flD = floorf(posD);
  float fd  = posD - flD;
  int dlo = (int)flD, dhi = dlo + 1;
  float wd0 = (dlo >= 0 && dlo <= 7) ? (1.0f - fd) : 0.0f;
  float wd1 = (dhi >= 0 && dhi <= 7) ? fd : 0.0f;
  int d0 = min(max(dlo, 0), 7) * 49;
  int d1 = min(max(dhi, 0), 7) * 49;

  // ---- rotation by inverse(e_i) ----
  float inv = fmodf(-ti, TWO_PI_F);
  if (inv < 0.0f) inv += TWO_PI_F;
  float cs = cosf(inv), sn = sinf(inv);
  float gx = (float)(uu - 3) * (1.0f / 3.0f);
  float gy = (float)(vv - 3) * (1.0f / 3.0f);
  float rx = cs * gx - sn * gy;
  float ry = sn * gx + cs * gy;

  // ---- H axis (rx) ----
  float posH = (rx + 1.0f) * 0.5f * 6.0f;
  float flH = floorf(posH);
  float fh  = posH - flH;
  int hlo = (int)flH, hhi = hlo + 1;
  float wh0 = (hlo >= 0 && hlo <= 6) ? (1.0f - fh) : 0.0f;
  float wh1 = (hhi >= 0 && hhi <= 6) ? fh : 0.0f;
  int h0 = min(max(hlo, 0), 6) * 7;
  int h1 = min(max(hhi, 0), 6) * 7;

  // ---- W axis (ry) ----
  float posW = (ry + 1.0f) * 0.5f * 6.0f;
  float flW = floorf(posW);
  float fw  = posW - flW;
  int wlo = (int)flW, whi = wlo + 1;
  float wq0 = (wlo >= 0 && wlo <= 6) ? (1.0f - fw) : 0.0f;
  float wq1 = (whi >= 0 && whi <= 6) ? fw : 0.0f;
  int q0 = min(max(wlo, 0), 6);
  int q1 = min(max(whi, 0), 6);
  // ==========================================================================

  // d-axis: dominant slice only (validated r4/r8)
  float Wd; int db;
  if (wd1 > wd0) { Wd = wd1; db = d1; } else { Wd = wd0; db = d0; }

  const int o   = c0 >> 7;
  const int ic0 = c0 & 127;
  float* op = out + (size_t)((o * 8 + gi) * 128 + ic0) * JUV + juv;

  if ((gi & 1) == 0) {
    // exact grid symmetry: single dominant tap per spatial axis (validated)
    float Wh; int hb;
    if (wh1 > wh0) { Wh = wh1; hb = h1; } else { Wh = wh0; hb = h0; }
    float Ww; int qb;
    if (wq1 > wq0) { Ww = wq1; qb = q1; } else { Ww = wq0; qb = q0; }
    const float W = Wd * Wh * Ww;
    const int off = db + hb + qb;
    #pragma unroll
    for (int c = 0; c < C; ++c) {
      __builtin_nontemporal_store(lds[c * JUV + off] * W, op);
      op += JUV;
    }
  } else {
    // 2x2 spatial bilinear in the dominant d slice (validated)
    const float w00 = Wd * wh0 * wq0, w01 = Wd * wh0 * wq1;
    const float w10 = Wd * wh1 * wq0, w11 = Wd * wh1 * wq1;
    const int o00 = db + h0 + q0, o01 = db + h0 + q1;
    const int o10 = db + h1 + q0, o11 = db + h1 + q1;
    #pragma unroll
    for (int c = 0; c < C; ++c) {
      const float* s = lds + c * JUV;
      float acc = s[o00] * w00 + s[o01] * w01
                + s[o10] * w10 + s[o11] * w11;
      __builtin_nontemporal_store(acc, op);
      op += JUV;
    }
  }
}

extern "C" void kernel_launch(void* const* d_in, const int* in_sizes, int n_in,
                              void* d_out, int out_size, void* d_ws, size_t ws_size,
                              hipStream_t stream) {
  const float* w = (const float*)d_in[0];
  float* out = (float*)d_out;
  const int blocks = 8 * (128 * 128 / C);   // 8192
  hipLaunchKernelGGL(lift9, dim3(blocks), dim3(BLOCK), 0, stream, w, out);
}

// Round 10
// 70.984 us; speedup vs baseline: 3.1265x; 1.0027x over previous
//
#include <hip/hip_runtime.h>
#include <math.h>

// r9 lineage (PASSING, 71us) + ONE delta: odd-gi 2x2 bilinear gathers use an
// UNCLAMPED base b = db + hlo*7 + wlo and read taps at {b, b+1, b+7, b+8}.
// The validity-masked weights (computed on unclamped hlo/whi/wlo/whi, as in
// the reference) are zero exactly when the unclamped address differs from the
// clamped one, so the weighted sum is bit-equivalent. Constant offsets let
// the compiler merge the 4 reads into 2x ds_read2_b32 (halves odd-gi LDS
// instruction count). LDS padded +-16 floats, pads zeroed (no NaN from 0*pad).
//
// out flat: ((((o*8 + gi)*128 + ic)*8 + j)*7 + u)*7 + v
// sig flat: ((o*128 + ic)*8 + d)*49 + h*7 + w

constexpr int BLOCK = 448;          // 7 waves; lanes 392..447 idle in compute
constexpr int JUV = 392;
constexpr int C = 16;               // channels per block (16 | 128 -> one 'o')
constexpr int PAD = 16;             // front/back pad floats (covers b in [-16, 6287])

__global__ __launch_bounds__(BLOCK)
void lift10(const float* __restrict__ sig, float* __restrict__ out) {
  __shared__ __align__(16) float lds_raw[PAD + C * JUV + PAD];
  float* lds = lds_raw + PAD;

  const int bid   = blockIdx.x;
  const int gi    = bid >> 10;           // 0..7
  const int chunk = bid & 1023;          // 0..1023
  const int c0    = chunk * C;

  // ---- zero pads, then stage chunk with coalesced float4 ----
  if (threadIdx.x < PAD) {
    lds_raw[threadIdx.x] = 0.0f;
    lds_raw[PAD + C * JUV + threadIdx.x] = 0.0f;
  }
  {
    const float4* src4 = (const float4*)(sig + (size_t)c0 * JUV);
    float4* dst4 = (float4*)lds;         // PAD=16 floats -> dst stays 16B aligned
    for (int idx = threadIdx.x; idx < C * JUV / 4; idx += BLOCK)
      dst4[idx] = src4[idx];
  }
  __syncthreads();

  const int juv = threadIdx.x;
  if (juv >= JUV) return;

  int j  = juv / 49;
  int uv = juv - j * 49;
  int uu = uv / 7;
  int vv = uv - uu * 7;

  // ================= tap computation (verified math, rounds 2-9) ===========
  const float TWO_PI_F = 6.28318530717958647692f;
  const float STEP = TWO_PI_F / 8.0f;

  float ti = (float)gi * STEP;
  float tj = (float)j  * STEP;

  // ---- D (group) axis ----
  float tH = fmodf(tj - ti, TWO_PI_F);
  if (tH < 0.0f) tH += TWO_PI_F;
  const float largest = TWO_PI_F * 7.0f / 8.0f;
  float cD = 2.0f * tH / largest - 1.0f;
  float posD = (cD + 1.0f) * 0.5f * 7.0f;
  float flD = floorf(posD);
  float fd  = posD - flD;
  int dlo = (int)flD, dhi = dlo + 1;
  float wd0 = (dlo >= 0 && dlo <= 7) ? (1.0f - fd) : 0.0f;
  float wd1 = (dhi >= 0 && dhi <= 7) ? fd : 0.0f;
  int d0 = min(max(dlo, 0), 7) * 49;
  int d1 = min(max(dhi, 0), 7) * 49;

  // ---- rotation by inverse(e_i) ----
  float inv = fmodf(-ti, TWO_PI_F);
  if (inv < 0.0f) inv += TWO_PI_F;
  float cs = cosf(inv), sn = sinf(inv);
  float gx = (float)(uu - 3) * (1.0f / 3.0f);
  float gy = (float)(vv - 3) * (1.0f / 3.0f);
  float rx = cs * gx - sn * gy;
  float ry = sn * gx + cs * gy;

  // ---- H axis (rx) ----
  float posH = (rx + 1.0f) * 0.5f * 6.0f;
  float flH = floorf(posH);
  float fh  = posH - flH;
  int hlo = (int)flH, hhi = hlo + 1;
  float wh0 = (hlo >= 0 && hlo <= 6) ? (1.0f - fh) : 0.0f;
  float wh1 = (hhi >= 0 && hhi <= 6) ? fh : 0.0f;
  int h0 = min(max(hlo, 0), 6) * 7;
  int h1 = min(max(hhi, 0), 6) * 7;

  // ---- W axis (ry) ----
  float posW = (ry + 1.0f) * 0.5f * 6.0f;
  float flW = floorf(posW);
  float fw  = posW - flW;
  int wlo = (int)flW, whi = wlo + 1;
  float wq0 = (wlo >= 0 && wlo <= 6) ? (1.0f - fw) : 0.0f;
  float wq1 = (whi >= 0 && whi <= 6) ? fw : 0.0f;
  int q0 = min(max(wlo, 0), 6);
  int q1 = min(max(whi, 0), 6);
  // ==========================================================================

  // d-axis: dominant slice only (validated r4/r8/r9)
  float Wd; int db;
  if (wd1 > wd0) { Wd = wd1; db = d1; } else { Wd = wd0; db = d0; }

  const int o   = c0 >> 7;
  const int ic0 = c0 & 127;
  float* op = out + (size_t)((o * 8 + gi) * 128 + ic0) * JUV + juv;

  if ((gi & 1) == 0) {
    // exact grid symmetry: single dominant tap per spatial axis (validated)
    float Wh; int hb;
    if (wh1 > wh0) { Wh = wh1; hb = h1; } else { Wh = wh0; hb = h0; }
    float Ww; int qb;
    if (wq1 > wq0) { Ww = wq1; qb = q1; } else { Ww = wq0; qb = q0; }
    const float W = Wd * Wh * Ww;
    const int off = db + hb + qb;
    #pragma unroll
    for (int c = 0; c < C; ++c) {
      __builtin_nontemporal_store(lds[c * JUV + off] * W, op);
      op += JUV;
    }
  } else {
    // 2x2 spatial bilinear, unclamped-base pair reads (equivalence proven by
    // masked weights; taps at b, b+1, b+7, b+8 -> 2x ds_read2_b32)
    const float w00 = Wd * wh0 * wq0, w01 = Wd * wh0 * wq1;
    const float w10 = Wd * wh1 * wq0, w11 = Wd * wh1 * wq1;
    const int b = db + hlo * 7 + wlo;    // unclamped; in [-16, 399]
    #pragma unroll
    for (int c = 0; c < C; ++c) {
      const float* s = lds + c * JUV + b;
      float acc = s[0] * w00 + s[1] * w01
                + s[7] * w10 + s[8] * w11;
      __builtin_nontemporal_store(acc, op);
      op += JUV;
    }
  }
}

extern "C" void kernel_launch(void* const* d_in, const int* in_sizes, int n_in,
                              void* d_out, int out_size, void* d_ws, size_t ws_size,
                              hipStream_t stream) {
  const float* w = (const float*)d_in[0];
  float* out = (float*)d_out;
  const int blocks = 8 * (128 * 128 / C);   // 8192
  hipLaunchKernelGGL(lift10, dim3(blocks), dim3(BLOCK), 0, stream, w, out);
}

// Round 11
// 60.625 us; speedup vs baseline: 3.6608x; 1.1709x over previous
//
#include <hip/hip_runtime.h>
#include <math.h>

// r10 lineage (PASSING, 71us) + ONE delta: blockIdx decode makes the 8
// gi-blocks of each chunk (a) SAME XCD (bids equal mod 8 -> one L2 copy, the
// r8 win) and (b) TEMPORALLY ADJACENT (bids within a 64-wide window -> the
// chunk is still L2-resident when all 8 read it; the old decode spaced them
// 1024 bids apart, letting the 205 MB write stream flush L2/L3 between
// readers — suspected cause of the ~2x fetch overshoot).
// Decode: s=bid>>6, gi=(bid>>3)&7, x=bid&7, chunk=8s+x. Bijective on
// (gi,chunk): zero semantic change.
//
// out flat: ((((o*8 + gi)*128 + ic)*8 + j)*7 + u)*7 + v
// sig flat: ((o*128 + ic)*8 + d)*49 + h*7 + w

constexpr int BLOCK = 448;          // 7 waves; lanes 392..447 idle in compute
constexpr int JUV = 392;
constexpr int C = 16;               // channels per block (16 | 128 -> one 'o')
constexpr int PAD = 16;             // front/back pad floats

__global__ __launch_bounds__(BLOCK)
void lift11(const float* __restrict__ sig, float* __restrict__ out) {
  __shared__ __align__(16) float lds_raw[PAD + C * JUV + PAD];
  float* lds = lds_raw + PAD;

  const int bid   = blockIdx.x;
  const int gi    = (bid >> 3) & 7;                  // 0..7
  const int chunk = ((bid >> 6) << 3) | (bid & 7);   // 0..1023
  const int c0    = chunk * C;

  // ---- zero pads, then stage chunk with coalesced float4 ----
  if (threadIdx.x < PAD) {
    lds_raw[threadIdx.x] = 0.0f;
    lds_raw[PAD + C * JUV + threadIdx.x] = 0.0f;
  }
  {
    const float4* src4 = (const float4*)(sig + (size_t)c0 * JUV);
    float4* dst4 = (float4*)lds;         // PAD=16 floats -> dst stays 16B aligned
    for (int idx = threadIdx.x; idx < C * JUV / 4; idx += BLOCK)
      dst4[idx] = src4[idx];
  }
  __syncthreads();

  const int juv = threadIdx.x;
  if (juv >= JUV) return;

  int j  = juv / 49;
  int uv = juv - j * 49;
  int uu = uv / 7;
  int vv = uv - uu * 7;

  // ================= tap computation (verified math, rounds 2-10) ==========
  const float TWO_PI_F = 6.28318530717958647692f;
  const float STEP = TWO_PI_F / 8.0f;

  float ti = (float)gi * STEP;
  float tj = (float)j  * STEP;

  // ---- D (group) axis ----
  float tH = fmodf(tj - ti, TWO_PI_F);
  if (tH < 0.0f) tH += TWO_PI_F;
  const float largest = TWO_PI_F * 7.0f / 8.0f;
  float cD = 2.0f * tH / largest - 1.0f;
  float posD = (cD + 1.0f) * 0.5f * 7.0f;
  float flD = floorf(posD);
  float fd  = posD - flD;
  int dlo = (int)flD, dhi = dlo + 1;
  float wd0 = (dlo >= 0 && dlo <= 7) ? (1.0f - fd) : 0.0f;
  float wd1 = (dhi >= 0 && dhi <= 7) ? fd : 0.0f;
  int d0 = min(max(dlo, 0), 7) * 49;
  int d1 = min(max(dhi, 0), 7) * 49;

  // ---- rotation by inverse(e_i) ----
  float inv = fmodf(-ti, TWO_PI_F);
  if (inv < 0.0f) inv += TWO_PI_F;
  float cs = cosf(inv), sn = sinf(inv);
  float gx = (float)(uu - 3) * (1.0f / 3.0f);
  float gy = (float)(vv - 3) * (1.0f / 3.0f);
  float rx = cs * gx - sn * gy;
  float ry = sn * gx + cs * gy;

  // ---- H axis (rx) ----
  float posH = (rx + 1.0f) * 0.5f * 6.0f;
  float flH = floorf(posH);
  float fh  = posH - flH;
  int hlo = (int)flH, hhi = hlo + 1;
  float wh0 = (hlo >= 0 && hlo <= 6) ? (1.0f - fh) : 0.0f;
  float wh1 = (hhi >= 0 && hhi <= 6) ? fh : 0.0f;
  int h0 = min(max(hlo, 0), 6) * 7;
  int h1 = min(max(hhi, 0), 6) * 7;

  // ---- W axis (ry) ----
  float posW = (ry + 1.0f) * 0.5f * 6.0f;
  float flW = floorf(posW);
  float fw  = posW - flW;
  int wlo = (int)flW, whi = wlo + 1;
  float wq0 = (wlo >= 0 && wlo <= 6) ? (1.0f - fw) : 0.0f;
  float wq1 = (whi >= 0 && whi <= 6) ? fw : 0.0f;
  int q0 = min(max(wlo, 0), 6);
  int q1 = min(max(whi, 0), 6);
  // ==========================================================================

  // d-axis: dominant slice only (validated r4/r8/r9/r10)
  float Wd; int db;
  if (wd1 > wd0) { Wd = wd1; db = d1; } else { Wd = wd0; db = d0; }

  const int o   = c0 >> 7;
  const int ic0 = c0 & 127;
  float* op = out + (size_t)((o * 8 + gi) * 128 + ic0) * JUV + juv;

  if ((gi & 1) == 0) {
    // exact grid symmetry: single dominant tap per spatial axis (validated)
    float Wh; int hb;
    if (wh1 > wh0) { Wh = wh1; hb = h1; } else { Wh = wh0; hb = h0; }
    float Ww; int qb;
    if (wq1 > wq0) { Ww = wq1; qb = q1; } else { Ww = wq0; qb = q0; }
    const float W = Wd * Wh * Ww;
    const int off = db + hb + qb;
    #pragma unroll
    for (int c = 0; c < C; ++c) {
      __builtin_nontemporal_store(lds[c * JUV + off] * W, op);
      op += JUV;
    }
  } else {
    // 2x2 spatial bilinear, unclamped-base pair reads (validated r10)
    const float w00 = Wd * wh0 * wq0, w01 = Wd * wh0 * wq1;
    const float w10 = Wd * wh1 * wq0, w11 = Wd * wh1 * wq1;
    const int b = db + hlo * 7 + wlo;    // unclamped; pads cover OOB
    #pragma unroll
    for (int c = 0; c < C; ++c) {
      const float* s = lds + c * JUV + b;
      float acc = s[0] * w00 + s[1] * w01
                + s[7] * w10 + s[8] * w11;
      __builtin_nontemporal_store(acc, op);
      op += JUV;
    }
  }
}

extern "C" void kernel_launch(void* const* d_in, const int* in_sizes, int n_in,
                              void* d_out, int out_size, void* d_ws, size_t ws_size,
                              hipStream_t stream) {
  const float* w = (const float*)d_in[0];
  float* out = (float*)d_out;
  const int blocks = 8 * (128 * 128 / C);   // 8192
  hipLaunchKernelGGL(lift11, dim3(blocks), dim3(BLOCK), 0, stream, w, out);
}